// Round 4
// baseline (171.966 us; speedup 1.0000x reference)
//
#include <hip/hip_runtime.h>
#include <math.h>

#define N_ 2048
#define D_ 1024
#define TOPK 10
#define TOPK_HALF 5
#define INV_NORM (1.0f / ((float)N_ * (float)(N_ - 1)))

typedef __attribute__((ext_vector_type(8))) short short8;
typedef __attribute__((ext_vector_type(4))) float floatx4;

__device__ __forceinline__ short f2bf(float f) {
  unsigned u = __float_as_uint(f);
  unsigned r = (u + 0x7fffu + ((u >> 16) & 1u)) >> 16;
  return (short)r;
}
__device__ __forceinline__ float bf2f(short b) {
  return __uint_as_float(((unsigned)(unsigned short)b) << 16);
}

__device__ __forceinline__ void gld_lds16(const short* g, short* l) {
  __builtin_amdgcn_global_load_lds(
      (const __attribute__((address_space(1))) unsigned int*)(g),
      (__attribute__((address_space(3))) unsigned int*)(l), 16, 0, 0);
}

// ---------- prep: normalize t -> bf16 (+tt), convert s -> bf16 (+ss); zero rowsum & out ----------
__global__ __launch_bounds__(256) void prep_kernel(const float* __restrict__ t,
                                                   const float* __restrict__ s,
                                                   short* __restrict__ tb,
                                                   short* __restrict__ sb,
                                                   float* __restrict__ tt,
                                                   float* __restrict__ ss,
                                                   float* __restrict__ rowsum,
                                                   float* __restrict__ out) {
  int b = blockIdx.x, tid = threadIdx.x;
  __shared__ float red[256];
  if (b == 0) {
    for (int j = tid; j < N_; j += 256) rowsum[j] = 0.f;
    if (tid == 0) out[0] = 0.f;
  }
  if (b < N_) {  // tnorm row b
    const float* rp = t + (size_t)b * D_;
    short* op = tb + (size_t)b * D_;
    float acc = 0.f;
    for (int k = tid; k < D_; k += 256) { float v = rp[k]; acc += v * v; }
    red[tid] = acc; __syncthreads();
    for (int st = 128; st > 0; st >>= 1) { if (tid < st) red[tid] += red[tid + st]; __syncthreads(); }
    float denom = fmaxf(sqrtf(red[0]), 1e-12f);
    __syncthreads();
    float s2 = 0.f;
    for (int k = tid; k < D_; k += 256) { float v = rp[k] / denom; op[k] = f2bf(v); s2 += v * v; }
    red[tid] = s2; __syncthreads();
    for (int st = 128; st > 0; st >>= 1) { if (tid < st) red[tid] += red[tid + st]; __syncthreads(); }
    if (tid == 0) tt[b] = red[0];
  } else {  // sconv row b-N_
    int row = b - N_;
    const float* rp = s + (size_t)row * D_;
    short* op = sb + (size_t)row * D_;
    float acc = 0.f;
    for (int k = tid; k < D_; k += 256) { float v = rp[k]; op[k] = f2bf(v); acc += v * v; }
    red[tid] = acc; __syncthreads();
    for (int st = 128; st > 0; st >>= 1) { if (tid < st) red[tid] += red[tid + st]; __syncthreads(); }
    if (tid == 0) ss[row] = red[0];
  }
}

// ---------- fused bf16-MFMA Gram, bf16 output; mode 1 also accumulates S row sums ----------
__global__ __launch_bounds__(256) void gram_mfma_kernel(
    const short* __restrict__ Tb, const short* __restrict__ Sb,
    const float* __restrict__ tt, const float* __restrict__ ss,
    short* __restrict__ WPb, short* __restrict__ Sob,
    float* __restrict__ rowsum) {
  const int mode = blockIdx.z;
  const short* A = mode ? Sb : Tb;
  const float* rn = mode ? ss : tt;
  short* outb = mode ? Sob : WPb;

  __shared__ __align__(16) short As[128 * 64];
  __shared__ __align__(16) short Bs[128 * 64];

  int tid = threadIdx.x;
  int w = tid >> 6, lane = tid & 63;
  int i0 = blockIdx.y * 128, j0 = blockIdx.x * 128;
  int wr = w >> 1, wc = w & 1;
  int quad = lane >> 4, l16 = lane & 15;

  floatx4 acc[4][4] = {};

  int srow = w * 32 + (lane >> 3);
  int scol = (lane & 7) * 8;
  const short* Ag = A + (size_t)(i0 + srow) * D_ + scol;
  const short* Bg = A + (size_t)(j0 + srow) * D_ + scol;
  short* Al = As + srow * 64 + scol;
  short* Bl = Bs + srow * 64 + scol;

  for (int k0 = 0; k0 < D_; k0 += 64) {
    __syncthreads();
#pragma unroll
    for (int q = 0; q < 4; q++) {
      gld_lds16(Ag + k0 + (size_t)q * 8 * D_, Al + q * 8 * 64);
      gld_lds16(Bg + k0 + (size_t)q * 8 * D_, Bl + q * 8 * 64);
    }
    __syncthreads();
#pragma unroll
    for (int ks = 0; ks < 64; ks += 32) {
      short8 af[4], bfr[4];
#pragma unroll
      for (int mt = 0; mt < 4; mt++)
        af[mt] = *(const short8*)&As[(wr * 64 + mt * 16 + l16) * 64 + ks + quad * 8];
#pragma unroll
      for (int nt = 0; nt < 4; nt++)
        bfr[nt] = *(const short8*)&Bs[(wc * 64 + nt * 16 + l16) * 64 + ks + quad * 8];
#pragma unroll
      for (int mt = 0; mt < 4; mt++)
#pragma unroll
        for (int nt = 0; nt < 4; nt++)
          acc[mt][nt] = __builtin_amdgcn_mfma_f32_16x16x32_bf16(af[mt], bfr[nt], acc[mt][nt], 0, 0, 0);
    }
  }

#pragma unroll
  for (int mt = 0; mt < 4; mt++) {
#pragma unroll
    for (int r = 0; r < 4; r++) {
      int i = i0 + wr * 64 + mt * 16 + quad * 4 + r;
      float ri = rn[i];
      float rs = 0.f;
#pragma unroll
      for (int nt = 0; nt < 4; nt++) {
        int j = j0 + wc * 64 + nt * 16 + l16;
        float d2 = fmaxf(ri + rn[j] - 2.f * acc[mt][nt][r], 0.f);
        float o = mode ? sqrtf(d2) : expf(-d2);
        if (i == j) o = mode ? 0.f : 1.f;
        outb[(size_t)i * N_ + j] = f2bf(o);
        rs += o;
      }
      if (mode) {
        rs += __shfl_xor(rs, 1); rs += __shfl_xor(rs, 2);
        rs += __shfl_xor(rs, 4); rs += __shfl_xor(rs, 8);
        if (l16 == 0) atomicAdd(&rowsum[i], rs);
      }
    }
  }
}

// ---------- per-row: dense loss partial (atomicAdd into out) + top-10 ----------
__global__ __launch_bounds__(256) void topk_loss_kernel(const short* __restrict__ WPb,
                                                        const short* __restrict__ Sb,
                                                        const float* __restrict__ rowsum,
                                                        int* __restrict__ idx,
                                                        float* __restrict__ out) {
  int row = blockIdx.x, tid = threadIdx.x;
  short8 wp8 = ((const short8*)(WPb + (size_t)row * N_))[tid];
  short8 s8 = ((const short8*)(Sb + (size_t)row * N_))[tid];
  float w[8];
  float rminv = (float)N_ / rowsum[row];
  float local = 0.f;
#pragma unroll
  for (int c = 0; c < 8; c++) {
    w[c] = bf2f(wp8[c]);
    float sv = bf2f(s8[c]) * rminv;
    float d = fmaxf(1.0f - sv, 0.f);
    local += d * d + 0.5f * w[c] * (sv * sv - d * d);
  }
  __shared__ float red[256];
  __shared__ float wv[4];
  __shared__ int wi[4];
  red[tid] = local; __syncthreads();
  for (int st = 128; st > 0; st >>= 1) { if (tid < st) red[tid] += red[tid + st]; __syncthreads(); }
  if (tid == 0) atomicAdd(out, (red[0] - 0.5f) * INV_NORM);  // diag term removed

  // top-10 from register copies (threads own j = tid*8+c)
  for (int t = 0; t < TOPK; t++) {
    float bv = -2.f; int bi = 0;
#pragma unroll
    for (int c = 0; c < 8; c++)
      if (w[c] > bv) { bv = w[c]; bi = tid * 8 + c; }  // ascending c => lowest j in thread
#pragma unroll
    for (int off = 32; off > 0; off >>= 1) {
      float ov = __shfl_down(bv, off);
      int oi = __shfl_down(bi, off);
      if (ov > bv || (ov == bv && oi < bi)) { bv = ov; bi = oi; }
    }
    __syncthreads();  // protect wv/wi reuse across rounds
    if ((tid & 63) == 0) { wv[tid >> 6] = bv; wi[tid >> 6] = bi; }
    __syncthreads();
    float b0 = wv[0]; int j0w = wi[0];
#pragma unroll
    for (int u = 1; u < 4; u++)
      if (wv[u] > b0 || (wv[u] == b0 && wi[u] < j0w)) { b0 = wv[u]; j0w = wi[u]; }
    if (tid == 0) idx[row * TOPK + t] = j0w;
    if ((j0w >> 3) == tid) w[j0w & 7] = -1.f;
  }
}

// ---------- mutual kNN adjacency (V), per-row neighbor lists ----------
__global__ void mutual_kernel(const int* __restrict__ idx, int* __restrict__ nbr,
                              int* __restrict__ deg) {
  int i = blockIdx.x * blockDim.x + threadIdx.x;
  if (i >= N_) return;
  int cnt = 0;
  for (int k = 0; k < TOPK; k++) {
    int j = idx[i * TOPK + k];
    bool mut = false;
    for (int l = 0; l < TOPK; l++)
      if (idx[j * TOPK + l] == i) mut = true;
    if (mut) nbr[i * TOPK + cnt++] = j;
  }
  deg[i] = cnt;
}

// ---------- sparse W_C loss: one thread per (i, mi, k); overlap computed inline ----------
__global__ __launch_bounds__(256) void sparse_wc_kernel(
    const int* __restrict__ idx, const int* __restrict__ nbr,
    const int* __restrict__ deg, const short* __restrict__ Sb,
    const float* __restrict__ rowsum, float* __restrict__ out) {
  int t = blockIdx.x * 256 + threadIdx.x;
  int i = t / (TOPK_HALF * TOPK);
  int r = t % (TOPK_HALF * TOPK);
  int mi = r / TOPK, k = r % TOPK;
  float contrib = 0.f;
  if (i < N_) {
    int m = idx[i * TOPK + mi];
    int dm = deg[m];
    if (k < dm) {
      int col = nbr[m * TOPK + k];
      if (col != i) {
        int dj = deg[col];
        int c = 0;
        for (int a = 0; a < dm; a++) {
          int na = nbr[m * TOPK + a];
          for (int b = 0; b < dj; b++) c += (nbr[col * TOPK + b] == na);
        }
        float v = (float)c / (float)dm * 0.1f;  // W_C value at (i,col) & (col,i)
        float s1 = bf2f(Sb[(size_t)i * N_ + col]) * ((float)N_ / rowsum[i]);
        float d1 = fmaxf(1.f - s1, 0.f);
        float s2 = bf2f(Sb[(size_t)col * N_ + i]) * ((float)N_ / rowsum[col]);
        float d2 = fmaxf(1.f - s2, 0.f);
        contrib = 0.5f * v * ((s1 * s1 - d1 * d1) + (s2 * s2 - d2 * d2));
      }
    }
  }
  __shared__ float red[256];
  red[threadIdx.x] = contrib; __syncthreads();
  for (int st = 128; st > 0; st >>= 1) {
    if (threadIdx.x < st) red[threadIdx.x] += red[threadIdx.x + st];
    __syncthreads();
  }
  if (threadIdx.x == 0) atomicAdd(out, red[0] * INV_NORM);
}

#define SPARSE_BLOCKS ((N_ * TOPK_HALF * TOPK) / 256)

extern "C" void kernel_launch(void* const* d_in, const int* in_sizes, int n_in,
                              void* d_out, int out_size, void* d_ws, size_t ws_size,
                              hipStream_t stream) {
  const float* s_emb = (const float*)d_in[0];
  const float* t_emb = (const float*)d_in[1];
  float* out = (float*)d_out;

  const size_t NN = (size_t)N_ * N_;
  const size_t ND = (size_t)N_ * D_;
  short* t_bf = (short*)d_ws;                        // N*D bf16
  short* s_bf = t_bf + ND;                           // N*D bf16
  short* WPb = s_bf + ND;                            // N*N bf16
  short* Sb = WPb + NN;                              // N*N bf16
  float* tt = (float*)(Sb + NN);                     // N
  float* ss = tt + N_;                               // N
  float* rowsum = ss + N_;                           // N
  int* idx = (int*)(rowsum + N_);                    // N*TOPK
  int* nbr = idx + (size_t)N_ * TOPK;                // N*TOPK
  int* deg = nbr + (size_t)N_ * TOPK;                // N

  prep_kernel<<<2 * N_, 256, 0, stream>>>(t_emb, s_emb, t_bf, s_bf, tt, ss, rowsum, out);

  dim3 g(N_ / 128, N_ / 128, 2);
  gram_mfma_kernel<<<g, 256, 0, stream>>>(t_bf, s_bf, tt, ss, WPb, Sb, rowsum);

  topk_loss_kernel<<<N_, 256, 0, stream>>>(WPb, Sb, rowsum, idx, out);
  mutual_kernel<<<N_ / 256, 256, 0, stream>>>(idx, nbr, deg);
  sparse_wc_kernel<<<SPARSE_BLOCKS, 256, 0, stream>>>(idx, nbr, deg, Sb, rowsum, out);
}

// Round 5
// 149.713 us; speedup vs baseline: 1.1486x; 1.1486x over previous
//
#include <hip/hip_runtime.h>
#include <math.h>

#define N_ 2048
#define D_ 1024
#define TOPK 10
#define TOPK_HALF 5
#define INV_NORM (1.0f / ((float)N_ * (float)(N_ - 1)))

typedef __attribute__((ext_vector_type(8))) short short8;
typedef __attribute__((ext_vector_type(4))) float floatx4;

__device__ __forceinline__ short f2bf(float f) {
  unsigned u = __float_as_uint(f);
  unsigned r = (u + 0x7fffu + ((u >> 16) & 1u)) >> 16;
  return (short)r;
}
__device__ __forceinline__ float bf2f(short b) {
  return __uint_as_float(((unsigned)(unsigned short)b) << 16);
}

__device__ __forceinline__ void gld_lds16(const short* g, short* l) {
  __builtin_amdgcn_global_load_lds(
      (const __attribute__((address_space(1))) unsigned int*)(g),
      (__attribute__((address_space(3))) unsigned int*)(l), 16, 0, 0);
}

// raw barriers: avoid compiler's s_waitcnt vmcnt(0) drain at __syncthreads
#define BAR() asm volatile("s_barrier" ::: "memory")
#define WAIT8_BAR() asm volatile("s_waitcnt vmcnt(8)\ns_barrier" ::: "memory")
#define WAIT0_BAR() asm volatile("s_waitcnt vmcnt(0)\ns_barrier" ::: "memory")

// ---------- prep: normalize t -> bf16 (+tt), convert s -> bf16 (+ss); zero rowsum & out ----------
__global__ __launch_bounds__(256) void prep_kernel(const float* __restrict__ t,
                                                   const float* __restrict__ s,
                                                   short* __restrict__ tb,
                                                   short* __restrict__ sb,
                                                   float* __restrict__ tt,
                                                   float* __restrict__ ss,
                                                   float* __restrict__ rowsum,
                                                   float* __restrict__ out) {
  int b = blockIdx.x, tid = threadIdx.x;
  __shared__ float red[256];
  if (b == 0) {
    for (int j = tid; j < N_; j += 256) rowsum[j] = 0.f;
    if (tid == 0) out[0] = 0.f;
  }
  if (b < N_) {  // tnorm row b
    const float* rp = t + (size_t)b * D_;
    short* op = tb + (size_t)b * D_;
    float acc = 0.f;
    for (int k = tid; k < D_; k += 256) { float v = rp[k]; acc += v * v; }
    red[tid] = acc; __syncthreads();
    for (int st = 128; st > 0; st >>= 1) { if (tid < st) red[tid] += red[tid + st]; __syncthreads(); }
    float denom = fmaxf(sqrtf(red[0]), 1e-12f);
    __syncthreads();
    float s2 = 0.f;
    for (int k = tid; k < D_; k += 256) { float v = rp[k] / denom; op[k] = f2bf(v); s2 += v * v; }
    red[tid] = s2; __syncthreads();
    for (int st = 128; st > 0; st >>= 1) { if (tid < st) red[tid] += red[tid + st]; __syncthreads(); }
    if (tid == 0) tt[b] = red[0];
  } else {  // sconv row b-N_
    int row = b - N_;
    const float* rp = s + (size_t)row * D_;
    short* op = sb + (size_t)row * D_;
    float acc = 0.f;
    for (int k = tid; k < D_; k += 256) { float v = rp[k]; op[k] = f2bf(v); acc += v * v; }
    red[tid] = acc; __syncthreads();
    for (int st = 128; st > 0; st >>= 1) { if (tid < st) red[tid] += red[tid + st]; __syncthreads(); }
    if (tid == 0) ss[row] = red[0];
  }
}

// ---------- bf16-MFMA Gram, double-buffered LDS + XOR chunk swizzle ----------
// z==0: W_P = exp(-d2) from Tb/tt ; z==1: S = sqrt(d2) from Sb/ss (+ row sums)
__global__ __launch_bounds__(256) void gram_mfma_kernel(
    const short* __restrict__ Tb, const short* __restrict__ Sb,
    const float* __restrict__ tt, const float* __restrict__ ss,
    short* __restrict__ WPb, short* __restrict__ Sob,
    float* __restrict__ rowsum) {
  const int mode = blockIdx.z;
  const short* A = mode ? Sb : Tb;
  const float* rn = mode ? ss : tt;
  short* outb = mode ? Sob : WPb;

  __shared__ __align__(16) short As[2][128 * 64];
  __shared__ __align__(16) short Bs[2][128 * 64];

  int tid = threadIdx.x;
  int w = tid >> 6, lane = tid & 63;
  int i0 = blockIdx.y * 128, j0 = blockIdx.x * 128;
  int wr = w >> 1, wc = w & 1;
  int quad = lane >> 4, l16 = lane & 15;

  floatx4 acc[4][4] = {};

  // staging: lane -> row srow (+8 per q), physical chunk (lane&7); fetch swizzled
  // global chunk g = (lane&7) ^ (lane>>3) so logical chunk c of row r lands at
  // physical slot c ^ (r&7)
  int srow = w * 32 + (lane >> 3);
  int gchunk = ((lane & 7) ^ (lane >> 3)) * 8;
  const short* Ag = A + (size_t)(i0 + srow) * D_ + gchunk;
  const short* Bg = A + (size_t)(j0 + srow) * D_ + gchunk;
  int sloc = srow * 64 + (lane & 7) * 8;  // == lane*8 within each 8-row group

#define STAGE(buf, k0)                                        \
  do {                                                        \
    _Pragma("unroll") for (int q = 0; q < 4; q++) {           \
      gld_lds16(Ag + (k0) + (size_t)q * 8 * D_, &As[buf][sloc + q * 8 * 64]); \
      gld_lds16(Bg + (k0) + (size_t)q * 8 * D_, &Bs[buf][sloc + q * 8 * 64]); \
    }                                                         \
  } while (0)

  STAGE(0, 0);
#pragma unroll 2
  for (int it = 0; it < 16; it++) {
    int cur = it & 1;
    if (it) BAR();  // all waves done reading buf[cur^1] -> safe to overwrite
    if (it < 15) {
      STAGE(!cur, (it + 1) * 64);
      WAIT8_BAR();  // allow the 8 just-issued loads outstanding; cur slab done
    } else {
      WAIT0_BAR();
    }
    const short* Ab = As[cur];
    const short* Bb = Bs[cur];
#pragma unroll
    for (int ks = 0; ks < 64; ks += 32) {
      int cb = ks >> 3;
      short8 af[4], bfr[4];
#pragma unroll
      for (int mt = 0; mt < 4; mt++) {
        int r = wr * 64 + mt * 16 + l16;
        af[mt] = *(const short8*)&Ab[r * 64 + (((cb + quad) ^ (l16 & 7)) << 3)];
      }
#pragma unroll
      for (int nt = 0; nt < 4; nt++) {
        int r = wc * 64 + nt * 16 + l16;
        bfr[nt] = *(const short8*)&Bb[r * 64 + (((cb + quad) ^ (l16 & 7)) << 3)];
      }
#pragma unroll
      for (int mt = 0; mt < 4; mt++)
#pragma unroll
        for (int nt = 0; nt < 4; nt++)
          acc[mt][nt] = __builtin_amdgcn_mfma_f32_16x16x32_bf16(af[mt], bfr[nt], acc[mt][nt], 0, 0, 0);
    }
  }

#pragma unroll
  for (int mt = 0; mt < 4; mt++) {
#pragma unroll
    for (int r = 0; r < 4; r++) {
      int i = i0 + wr * 64 + mt * 16 + quad * 4 + r;
      float ri = rn[i];
      float rs = 0.f;
#pragma unroll
      for (int nt = 0; nt < 4; nt++) {
        int j = j0 + wc * 64 + nt * 16 + l16;
        float d2 = fmaxf(ri + rn[j] - 2.f * acc[mt][nt][r], 0.f);
        float o = mode ? sqrtf(d2) : expf(-d2);
        if (i == j) o = mode ? 0.f : 1.f;
        outb[(size_t)i * N_ + j] = f2bf(o);
        rs += o;
      }
      if (mode) {
        rs += __shfl_xor(rs, 1); rs += __shfl_xor(rs, 2);
        rs += __shfl_xor(rs, 4); rs += __shfl_xor(rs, 8);
        if (l16 == 0) atomicAdd(&rowsum[i], rs);
      }
    }
  }
}

// ---------- wave-per-row: dense loss partial + register-resident top-10 ----------
__global__ __launch_bounds__(64) void topk_loss_kernel(const short* __restrict__ WPb,
                                                       const short* __restrict__ Sb,
                                                       const float* __restrict__ rowsum,
                                                       int* __restrict__ idx,
                                                       unsigned* __restrict__ mask,
                                                       float* __restrict__ out) {
  int row = blockIdx.x, lane = threadIdx.x;
  const short8* wpr = (const short8*)(WPb + (size_t)row * N_);
  const short8* sr = (const short8*)(Sb + (size_t)row * N_);
  float rminv = (float)N_ / rowsum[row];
  float w[32];
  float local = 0.f;
#pragma unroll
  for (int c4 = 0; c4 < 4; c4++) {
    short8 wp8 = wpr[lane * 4 + c4];
    short8 s8 = sr[lane * 4 + c4];
#pragma unroll
    for (int e = 0; e < 8; e++) {
      float wv = bf2f(wp8[e]);
      w[c4 * 8 + e] = wv;
      float sv = bf2f(s8[e]) * rminv;
      float d = fmaxf(1.f - sv, 0.f);
      local += d * d + 0.5f * wv * (sv * sv - d * d);
    }
  }
#pragma unroll
  for (int off = 32; off > 0; off >>= 1) local += __shfl_down(local, off);
  if (lane == 0) {
    atomicAdd(out, (local - 0.5f) * INV_NORM);  // subtract diag term
    mask[row] = 0u;                             // zero for mutual_kernel
  }
  // top-10: lane owns j = lane*32 + c; strict > keeps lowest j on ties
  int base = lane * 32;
  int sel[TOPK];
  for (int t = 0; t < TOPK; t++) {
    float bv = -2.f; int bi = 0;
#pragma unroll
    for (int c = 0; c < 32; c++)
      if (w[c] > bv) { bv = w[c]; bi = base + c; }
#pragma unroll
    for (int off = 32; off > 0; off >>= 1) {
      float ov = __shfl_down(bv, off);
      int oi = __shfl_down(bi, off);
      if (ov > bv || (ov == bv && oi < bi)) { bv = ov; bi = oi; }
    }
    bi = __shfl(bi, 0);
    sel[t] = bi;
    bool mine = (bi >> 5) == lane;
    int cc = bi & 31;
#pragma unroll
    for (int c = 0; c < 32; c++)
      if (mine && cc == c) w[c] = -1.f;
  }
  if (lane == 0) {
#pragma unroll
    for (int t = 0; t < TOPK; t++) idx[row * TOPK + t] = sel[t];
  }
}

// ---------- mutual kNN as bitmask: one thread per (i,k) ----------
__global__ __launch_bounds__(256) void mutual_kernel(const int* __restrict__ idx,
                                                     unsigned* __restrict__ mask) {
  int t = blockIdx.x * 256 + threadIdx.x;
  int i = t >> 4, k = t & 15;
  if (i >= N_ || k >= TOPK) return;
  int j = idx[i * TOPK + k];
  bool mut = false;
#pragma unroll
  for (int l = 0; l < TOPK; l++) mut |= (idx[j * TOPK + l] == i);
  if (mut) atomicOr(&mask[i], 1u << k);
}

// ---------- sparse W_C part via masks: one thread per (i, mi, k) ----------
__global__ __launch_bounds__(256) void sparse_wc_kernel(
    const int* __restrict__ idx, const unsigned* __restrict__ mask,
    const short* __restrict__ Sb, const float* __restrict__ rowsum,
    float* __restrict__ out) {
  int t = blockIdx.x * 256 + threadIdx.x;
  int i = t >> 6, r = t & 63;
  float contrib = 0.f;
  if (i < N_ && r < TOPK_HALF * TOPK) {
    int mi = r / TOPK, k = r - mi * TOPK;
    int m = idx[i * TOPK + mi];
    unsigned mm = mask[m];
    if ((mm >> k) & 1u) {
      int col = idx[m * TOPK + k];
      if (col != i) {
        int dm = __popc(mm);
        unsigned mc = mask[col];
        int jm[TOPK], jc[TOPK];
#pragma unroll
        for (int l = 0; l < TOPK; l++) jm[l] = idx[m * TOPK + l];
#pragma unroll
        for (int l = 0; l < TOPK; l++) jc[l] = idx[col * TOPK + l];
        int c = 0;
#pragma unroll
        for (int a = 0; a < TOPK; a++) {
          if ((mm >> a) & 1u) {
            int na = jm[a];
#pragma unroll
            for (int b = 0; b < TOPK; b++) c += (((mc >> b) & 1u) && (jc[b] == na));
          }
        }
        float v = (float)c / (float)dm * 0.1f;  // (1/5 mean) * (1/2 symmetrize)
        float s1 = bf2f(Sb[(size_t)i * N_ + col]) * ((float)N_ / rowsum[i]);
        float d1 = fmaxf(1.f - s1, 0.f);
        float s2 = bf2f(Sb[(size_t)col * N_ + i]) * ((float)N_ / rowsum[col]);
        float d2 = fmaxf(1.f - s2, 0.f);
        contrib = 0.5f * v * ((s1 * s1 - d1 * d1) + (s2 * s2 - d2 * d2));
      }
    }
  }
  __shared__ float red[256];
  red[threadIdx.x] = contrib; __syncthreads();
  for (int st = 128; st > 0; st >>= 1) {
    if (threadIdx.x < st) red[threadIdx.x] += red[threadIdx.x + st];
    __syncthreads();
  }
  if (threadIdx.x == 0) atomicAdd(out, red[0] * INV_NORM);
}

extern "C" void kernel_launch(void* const* d_in, const int* in_sizes, int n_in,
                              void* d_out, int out_size, void* d_ws, size_t ws_size,
                              hipStream_t stream) {
  const float* s_emb = (const float*)d_in[0];
  const float* t_emb = (const float*)d_in[1];
  float* out = (float*)d_out;

  const size_t NN = (size_t)N_ * N_;
  const size_t ND = (size_t)N_ * D_;
  short* t_bf = (short*)d_ws;                        // N*D bf16
  short* s_bf = t_bf + ND;                           // N*D bf16
  short* WPb = s_bf + ND;                            // N*N bf16
  short* Sb = WPb + NN;                              // N*N bf16
  float* tt = (float*)(Sb + NN);                     // N
  float* ss = tt + N_;                               // N
  float* rowsum = ss + N_;                           // N
  int* idx = (int*)(rowsum + N_);                    // N*TOPK
  unsigned* mask = (unsigned*)(idx + (size_t)N_ * TOPK);  // N

  prep_kernel<<<2 * N_, 256, 0, stream>>>(t_emb, s_emb, t_bf, s_bf, tt, ss, rowsum, out);

  dim3 g(N_ / 128, N_ / 128, 2);
  gram_mfma_kernel<<<g, 256, 0, stream>>>(t_bf, s_bf, tt, ss, WPb, Sb, rowsum);

  topk_loss_kernel<<<N_, 64, 0, stream>>>(WPb, Sb, rowsum, idx, mask, out);
  mutual_kernel<<<N_ * 16 / 256, 256, 0, stream>>>(idx, mask);
  sparse_wc_kernel<<<N_ * 64 / 256, 256, 0, stream>>>(idx, mask, Sb, rowsum, out);
}

// Round 6
// 141.342 us; speedup vs baseline: 1.2167x; 1.0592x over previous
//
#include <hip/hip_runtime.h>
#include <math.h>

#define N_ 2048
#define D_ 1024
#define TOPK 10
#define TOPK_HALF 5
#define INV_NORM (1.0f / ((float)N_ * (float)(N_ - 1)))

typedef __attribute__((ext_vector_type(8))) short short8;
typedef __attribute__((ext_vector_type(4))) float floatx4;

__device__ __forceinline__ short f2bf(float f) {
  unsigned u = __float_as_uint(f);
  unsigned r = (u + 0x7fffu + ((u >> 16) & 1u)) >> 16;
  return (short)r;
}
__device__ __forceinline__ float bf2f(short b) {
  return __uint_as_float(((unsigned)(unsigned short)b) << 16);
}

__device__ __forceinline__ void gld_lds16(const short* g, short* l) {
  __builtin_amdgcn_global_load_lds(
      (const __attribute__((address_space(1))) unsigned int*)(g),
      (__attribute__((address_space(3))) unsigned int*)(l), 16, 0, 0);
}

#define BAR() asm volatile("s_barrier" ::: "memory")
#define WAIT4_BAR() asm volatile("s_waitcnt vmcnt(4)\ns_barrier" ::: "memory")
#define WAIT0_BAR() asm volatile("s_waitcnt vmcnt(0)\ns_barrier" ::: "memory")

// ---------- prep: normalize t -> bf16 (+tt), convert s -> bf16 (+ss); zero rowsum & out ----------
// one float4 per thread per row (D_ = 256 threads * 4)
__global__ __launch_bounds__(256) void prep_kernel(const float* __restrict__ t,
                                                   const float* __restrict__ s,
                                                   short* __restrict__ tb,
                                                   short* __restrict__ sb,
                                                   float* __restrict__ tt,
                                                   float* __restrict__ ss,
                                                   float* __restrict__ rowsum,
                                                   float* __restrict__ out) {
  int b = blockIdx.x, tid = threadIdx.x;
  __shared__ float red[256];
  if (b == 0) {
    for (int j = tid; j < N_; j += 256) rowsum[j] = 0.f;
    if (tid == 0) out[0] = 0.f;
  }
  if (b < N_) {  // tnorm row b
    const float4* rp = (const float4*)(t + (size_t)b * D_);
    float4 v = rp[tid];
    red[tid] = v.x * v.x + v.y * v.y + v.z * v.z + v.w * v.w;
    __syncthreads();
    for (int st = 128; st > 0; st >>= 1) { if (tid < st) red[tid] += red[tid + st]; __syncthreads(); }
    float inv = 1.f / fmaxf(sqrtf(red[0]), 1e-12f);
    __syncthreads();
    float a = v.x * inv, bb = v.y * inv, c = v.z * inv, d = v.w * inv;
    uint2 pk;
    pk.x = (unsigned)(unsigned short)f2bf(a) | ((unsigned)(unsigned short)f2bf(bb) << 16);
    pk.y = (unsigned)(unsigned short)f2bf(c) | ((unsigned)(unsigned short)f2bf(d) << 16);
    ((uint2*)(tb + (size_t)b * D_))[tid] = pk;
    red[tid] = a * a + bb * bb + c * c + d * d;
    __syncthreads();
    for (int st = 128; st > 0; st >>= 1) { if (tid < st) red[tid] += red[tid + st]; __syncthreads(); }
    if (tid == 0) tt[b] = red[0];
  } else {  // sconv row b-N_
    int row = b - N_;
    const float4* rp = (const float4*)(s + (size_t)row * D_);
    float4 v = rp[tid];
    uint2 pk;
    pk.x = (unsigned)(unsigned short)f2bf(v.x) | ((unsigned)(unsigned short)f2bf(v.y) << 16);
    pk.y = (unsigned)(unsigned short)f2bf(v.z) | ((unsigned)(unsigned short)f2bf(v.w) << 16);
    ((uint2*)(sb + (size_t)row * D_))[tid] = pk;
    red[tid] = v.x * v.x + v.y * v.y + v.z * v.z + v.w * v.w;
    __syncthreads();
    for (int st = 128; st > 0; st >>= 1) { if (tid < st) red[tid] += red[tid + st]; __syncthreads(); }
    if (tid == 0) ss[row] = red[0];
  }
}

// ---------- symmetric bf16-MFMA Gram: lower-triangle 64x64 blocks, dbuf LDS ----------
// 1056 blocks: [0,528) mode 0 (W_P), [528,1056) mode 1 (S + rowsum)
#define NTRI 528
__global__ __launch_bounds__(256) void gram_sym_kernel(
    const short* __restrict__ Tb, const short* __restrict__ Sb,
    const float* __restrict__ tt, const float* __restrict__ ss,
    short* __restrict__ WPb, short* __restrict__ Sob,
    float* __restrict__ rowsum) {
  int p = blockIdx.x;
  const int mode = (p >= NTRI);
  int q = p - mode * NTRI;
  int bi = (int)((sqrtf(8.f * (float)q + 1.f) - 1.f) * 0.5f);
  if (bi > 31) bi = 31;
  while ((bi + 1) * (bi + 2) / 2 <= q) bi++;
  while (bi * (bi + 1) / 2 > q) bi--;
  int bj = q - bi * (bi + 1) / 2;  // 0 <= bj <= bi

  const short* A = mode ? Sb : Tb;
  const float* rn = mode ? ss : tt;
  short* outb = mode ? Sob : WPb;

  // [buf][A/B] 64x64 bf16 slabs: 4 * 4096 shorts = 32 KB
  __shared__ __align__(16) short smem[4 * 4096];

  int tid = threadIdx.x;
  int w = tid >> 6, lane = tid & 63;
  int i0 = bi * 64, j0 = bj * 64;
  int wr = w >> 1, wc = w & 1;
  int quad = lane >> 4, l16 = lane & 15;

  floatx4 acc[2][2] = {};

  // staging: wave w stages rows [w*16, w*16+16) of each panel, 2 rounds of 8 rows
  int sr8 = lane >> 3;                       // 0..7
  int gch = ((lane & 7) ^ sr8) * 8;          // XOR-swizzled global chunk
  const short* Ag = A + (size_t)(i0 + w * 16 + sr8) * D_ + gch;
  const short* Bg = A + (size_t)(j0 + w * 16 + sr8) * D_ + gch;
  int lloc = (w * 16 + sr8) * 64 + (lane & 7) * 8;  // = wave_base + lane*8 elems

#define STAGE(buf, k0)                                                   \
  do {                                                                   \
    short* Al = smem + (buf)*8192 + lloc;                                \
    short* Bl = smem + (buf)*8192 + 4096 + lloc;                         \
    gld_lds16(Ag + (k0), Al);                                            \
    gld_lds16(Ag + (k0) + (size_t)8 * D_, Al + 512);                     \
    gld_lds16(Bg + (k0), Bl);                                            \
    gld_lds16(Bg + (k0) + (size_t)8 * D_, Bl + 512);                     \
  } while (0)

  STAGE(0, 0);
#pragma unroll 2
  for (int it = 0; it < 16; it++) {
    int cur = it & 1;
    if (it) BAR();
    if (it < 15) {
      STAGE(!cur, (it + 1) * 64);
      WAIT4_BAR();
    } else {
      WAIT0_BAR();
    }
    const short* Ab = smem + cur * 8192;
    const short* Bb = smem + cur * 8192 + 4096;
#pragma unroll
    for (int ks = 0; ks < 64; ks += 32) {
      int cb = ks >> 3;
      short8 af[2], bfr[2];
#pragma unroll
      for (int mt = 0; mt < 2; mt++) {
        int rr = wr * 32 + mt * 16 + l16;
        af[mt] = *(const short8*)&Ab[rr * 64 + (((cb + quad) ^ (l16 & 7)) << 3)];
      }
#pragma unroll
      for (int nt = 0; nt < 2; nt++) {
        int rr = wc * 32 + nt * 16 + l16;
        bfr[nt] = *(const short8*)&Bb[rr * 64 + (((cb + quad) ^ (l16 & 7)) << 3)];
      }
#pragma unroll
      for (int mt = 0; mt < 2; mt++)
#pragma unroll
        for (int nt = 0; nt < 2; nt++)
          acc[mt][nt] = __builtin_amdgcn_mfma_f32_16x16x32_bf16(af[mt], bfr[nt], acc[mt][nt], 0, 0, 0);
    }
  }

  // ---- epilogue: activate, direct store, row sums; then transposed tile ----
  float ov[2][2][4];
#pragma unroll
  for (int mt = 0; mt < 2; mt++) {
#pragma unroll
    for (int r = 0; r < 4; r++) {
      int i = i0 + wr * 32 + mt * 16 + quad * 4 + r;
      float ri = rn[i];
      float rs = 0.f;
#pragma unroll
      for (int nt = 0; nt < 2; nt++) {
        int j = j0 + wc * 32 + nt * 16 + l16;
        float d2 = fmaxf(ri + rn[j] - 2.f * acc[mt][nt][r], 0.f);
        float o = mode ? sqrtf(d2) : expf(-d2);
        if (i == j) o = mode ? 0.f : 1.f;
        ov[mt][nt][r] = o;
        outb[(size_t)i * N_ + j] = f2bf(o);
        rs += o;
      }
      if (mode) {
        rs += __shfl_xor(rs, 1); rs += __shfl_xor(rs, 2);
        rs += __shfl_xor(rs, 4); rs += __shfl_xor(rs, 8);
        if (l16 == 0) atomicAdd(&rowsum[i], rs);
      }
    }
  }

  if (bi != bj) {
    // column sums -> rowsum of transposed rows (mode 1 only)
    if (mode) {
#pragma unroll
      for (int nt = 0; nt < 2; nt++) {
        float cs = 0.f;
#pragma unroll
        for (int mt = 0; mt < 2; mt++)
#pragma unroll
          for (int r = 0; r < 4; r++) cs += ov[mt][nt][r];
        cs += __shfl_xor(cs, 16);
        cs += __shfl_xor(cs, 32);
        if (quad == 0) atomicAdd(&rowsum[j0 + wc * 32 + nt * 16 + l16], cs);
      }
    }
    // transposed store via wave-private LDS (32x32 fp32, pad 34)
    BAR();  // all waves done reading K-loop slabs before scratch overwrite
    float* fs = (float*)smem + w * 1088;  // 32*34 floats per wave
#pragma unroll
    for (int mt = 0; mt < 2; mt++)
#pragma unroll
      for (int nt = 0; nt < 2; nt++)
#pragma unroll
        for (int r = 0; r < 4; r++) {
          int lr = mt * 16 + quad * 4 + r;   // local row
          int lc = nt * 16 + l16;            // local col
          fs[lc * 34 + lr] = ov[mt][nt][r];
        }
    // read transposed rows, pack 2 bf16, coalesced dword stores
#pragma unroll
    for (int itx = 0; itx < 8; itx++) {
      int sidx = itx * 64 + lane;
      int lc = sidx >> 4;        // 0..31 transposed row
      int k2 = (sidx & 15) * 2;  // column pair
      float lo = fs[lc * 34 + k2];
      float hi = fs[lc * 34 + k2 + 1];
      unsigned pk = (unsigned)(unsigned short)f2bf(lo) |
                    ((unsigned)(unsigned short)f2bf(hi) << 16);
      size_t jg = (size_t)(j0 + wc * 32 + lc);
      *(unsigned*)(outb + jg * N_ + i0 + wr * 32 + k2) = pk;
    }
  }
}

// ---------- wave-per-row: dense loss partial + register-resident top-10 ----------
__global__ __launch_bounds__(64) void topk_loss_kernel(const short* __restrict__ WPb,
                                                       const short* __restrict__ Sb,
                                                       const float* __restrict__ rowsum,
                                                       int* __restrict__ idx,
                                                       unsigned* __restrict__ mask,
                                                       float* __restrict__ out) {
  int row = blockIdx.x, lane = threadIdx.x;
  const short8* wpr = (const short8*)(WPb + (size_t)row * N_);
  const short8* sr = (const short8*)(Sb + (size_t)row * N_);
  float rminv = (float)N_ / rowsum[row];
  float w[32];
  float local = 0.f;
#pragma unroll
  for (int c4 = 0; c4 < 4; c4++) {
    short8 wp8 = wpr[lane * 4 + c4];
    short8 s8 = sr[lane * 4 + c4];
#pragma unroll
    for (int e = 0; e < 8; e++) {
      float wv = bf2f(wp8[e]);
      w[c4 * 8 + e] = wv;
      float sv = bf2f(s8[e]) * rminv;
      float d = fmaxf(1.f - sv, 0.f);
      local += d * d + 0.5f * wv * (sv * sv - d * d);
    }
  }
#pragma unroll
  for (int off = 32; off > 0; off >>= 1) local += __shfl_down(local, off);
  if (lane == 0) {
    atomicAdd(out, (local - 0.5f) * INV_NORM);  // subtract diag term
    mask[row] = 0u;
  }
  int base = lane * 32;
  int sel[TOPK];
  for (int t = 0; t < TOPK; t++) {
    float bv = -2.f; int bi = 0;
#pragma unroll
    for (int c = 0; c < 32; c++)
      if (w[c] > bv) { bv = w[c]; bi = base + c; }
#pragma unroll
    for (int off = 32; off > 0; off >>= 1) {
      float ovv = __shfl_down(bv, off);
      int oi = __shfl_down(bi, off);
      if (ovv > bv || (ovv == bv && oi < bi)) { bv = ovv; bi = oi; }
    }
    bi = __shfl(bi, 0);
    sel[t] = bi;
    bool mine = (bi >> 5) == lane;
    int cc = bi & 31;
#pragma unroll
    for (int c = 0; c < 32; c++)
      if (mine && cc == c) w[c] = -1.f;
  }
  if (lane == 0) {
#pragma unroll
    for (int t = 0; t < TOPK; t++) idx[row * TOPK + t] = sel[t];
  }
}

// ---------- mutual kNN as bitmask: one thread per (i,k) ----------
__global__ __launch_bounds__(256) void mutual_kernel(const int* __restrict__ idx,
                                                     unsigned* __restrict__ mask) {
  int t = blockIdx.x * 256 + threadIdx.x;
  int i = t >> 4, k = t & 15;
  if (i >= N_ || k >= TOPK) return;
  int j = idx[i * TOPK + k];
  bool mut = false;
#pragma unroll
  for (int l = 0; l < TOPK; l++) mut |= (idx[j * TOPK + l] == i);
  if (mut) atomicOr(&mask[i], 1u << k);
}

// ---------- sparse W_C part via masks: one thread per (i, mi, k) ----------
__global__ __launch_bounds__(256) void sparse_wc_kernel(
    const int* __restrict__ idx, const unsigned* __restrict__ mask,
    const short* __restrict__ Sb, const float* __restrict__ rowsum,
    float* __restrict__ out) {
  int t = blockIdx.x * 256 + threadIdx.x;
  int i = t >> 6, r = t & 63;
  float contrib = 0.f;
  if (i < N_ && r < TOPK_HALF * TOPK) {
    int mi = r / TOPK, k = r - mi * TOPK;
    int m = idx[i * TOPK + mi];
    unsigned mm = mask[m];
    if ((mm >> k) & 1u) {
      int col = idx[m * TOPK + k];
      if (col != i) {
        int dm = __popc(mm);
        unsigned mc = mask[col];
        int jm[TOPK], jc[TOPK];
#pragma unroll
        for (int l = 0; l < TOPK; l++) jm[l] = idx[m * TOPK + l];
#pragma unroll
        for (int l = 0; l < TOPK; l++) jc[l] = idx[col * TOPK + l];
        int c = 0;
#pragma unroll
        for (int a = 0; a < TOPK; a++) {
          if ((mm >> a) & 1u) {
            int na = jm[a];
#pragma unroll
            for (int b = 0; b < TOPK; b++) c += (((mc >> b) & 1u) && (jc[b] == na));
          }
        }
        float v = (float)c / (float)dm * 0.1f;
        float s1 = bf2f(Sb[(size_t)i * N_ + col]) * ((float)N_ / rowsum[i]);
        float d1 = fmaxf(1.f - s1, 0.f);
        float s2 = bf2f(Sb[(size_t)col * N_ + i]) * ((float)N_ / rowsum[col]);
        float d2 = fmaxf(1.f - s2, 0.f);
        contrib = 0.5f * v * ((s1 * s1 - d1 * d1) + (s2 * s2 - d2 * d2));
      }
    }
  }
  __shared__ float red[256];
  red[threadIdx.x] = contrib; __syncthreads();
  for (int st = 128; st > 0; st >>= 1) {
    if (threadIdx.x < st) red[threadIdx.x] += red[threadIdx.x + st];
    __syncthreads();
  }
  if (threadIdx.x == 0) atomicAdd(out, red[0] * INV_NORM);
}

extern "C" void kernel_launch(void* const* d_in, const int* in_sizes, int n_in,
                              void* d_out, int out_size, void* d_ws, size_t ws_size,
                              hipStream_t stream) {
  const float* s_emb = (const float*)d_in[0];
  const float* t_emb = (const float*)d_in[1];
  float* out = (float*)d_out;

  const size_t NN = (size_t)N_ * N_;
  const size_t ND = (size_t)N_ * D_;
  short* t_bf = (short*)d_ws;                        // N*D bf16
  short* s_bf = t_bf + ND;                           // N*D bf16
  short* WPb = s_bf + ND;                            // N*N bf16
  short* Sb = WPb + NN;                              // N*N bf16
  float* tt = (float*)(Sb + NN);                     // N
  float* ss = tt + N_;                               // N
  float* rowsum = ss + N_;                           // N
  int* idx = (int*)(rowsum + N_);                    // N*TOPK
  unsigned* mask = (unsigned*)(idx + (size_t)N_ * TOPK);  // N

  prep_kernel<<<2 * N_, 256, 0, stream>>>(t_emb, s_emb, t_bf, s_bf, tt, ss, rowsum, out);

  gram_sym_kernel<<<2 * NTRI, 256, 0, stream>>>(t_bf, s_bf, tt, ss, WPb, Sb, rowsum);

  topk_loss_kernel<<<N_, 64, 0, stream>>>(WPb, Sb, rowsum, idx, mask, out);
  mutual_kernel<<<N_ * 16 / 256, 256, 0, stream>>>(idx, mask);
  sparse_wc_kernel<<<N_ * 64 / 256, 256, 0, stream>>>(idx, mask, Sb, rowsum, out);
}